// Round 1
// baseline (448.976 us; speedup 1.0000x reference)
//
#include <hip/hip_runtime.h>
#include <hip/hip_bf16.h>
#include <stdint.h>

#define N 8192
#define FIN 256
#define FOUT 64

typedef __attribute__((ext_vector_type(8))) short s8v;
typedef __attribute__((ext_vector_type(4))) float f4v;

// float -> bf16 bits, round-to-nearest-even
__device__ __forceinline__ uint32_t f2bf(float f) {
  uint32_t u = __float_as_uint(f);
  return (u + 0x7FFFu + ((u >> 16) & 1u)) >> 16;
}

// Kernel A: Wh = h@W (fp32 in regs), f1 = Wh@a1, f2 = Wh@a2, store WhT bf16 [64][8192]
__global__ __launch_bounds__(64) void gat_prep(
    const float* __restrict__ h, const float* __restrict__ W,
    const float* __restrict__ a,
    float* __restrict__ f1, float* __restrict__ f2,
    uint16_t* __restrict__ whT)
{
  const int c = threadIdx.x;        // 0..63 = output feature
  const int i0 = blockIdx.x * 8;    // 8 rows per block
  float acc[8] = {0.f, 0.f, 0.f, 0.f, 0.f, 0.f, 0.f, 0.f};
  #pragma unroll 4
  for (int k = 0; k < FIN; ++k) {
    float wv = W[k * FOUT + c];              // coalesced across lanes
    #pragma unroll
    for (int r = 0; r < 8; ++r)              // h index block-uniform -> s_load
      acc[r] += h[(size_t)(i0 + r) * FIN + k] * wv;
  }
  // lane c holds Wh[i0+r][c] == WhT[c][i0+r]: pack 8 bf16, one 16B store
  uint32_t b[8];
  #pragma unroll
  for (int r = 0; r < 8; ++r) b[r] = f2bf(acc[r]);
  int4 pk;
  pk.x = (int)(b[0] | (b[1] << 16));
  pk.y = (int)(b[2] | (b[3] << 16));
  pk.z = (int)(b[4] | (b[5] << 16));
  pk.w = (int)(b[6] | (b[7] << 16));
  *(int4*)(whT + (size_t)c * N + i0) = pk;

  const float a1 = a[c], a2 = a[FOUT + c];
  #pragma unroll
  for (int r = 0; r < 8; ++r) {
    float v1 = acc[r] * a1;
    float v2 = acc[r] * a2;
    #pragma unroll
    for (int m = 32; m > 0; m >>= 1) {
      v1 += __shfl_xor(v1, m, 64);
      v2 += __shfl_xor(v2, m, 64);
    }
    if (c == 0) { f1[i0 + r] = v1; f2[i0 + r] = v2; }
  }
}

// Kernel B: flash-style masked softmax + PV via bf16 MFMA.
// Block = 16 rows, 256 threads (4 waves, each wave owns a 16-col slice of FOUT).
__global__ __launch_bounds__(256) void gat_main(
    const int* __restrict__ adj, const float* __restrict__ f1,
    const float* __restrict__ f2, const uint16_t* __restrict__ whT,
    float* __restrict__ out)
{
  // +8 pad per row: stride 144B (16B-aligned, breaks pow2 bank pattern)
  __shared__ __align__(16) uint16_t w_lds[16][72];
  __shared__ __align__(16) uint16_t v_lds[64][72];
  __shared__ float den_lds[16][16];
  __shared__ float den_fin[16];

  const int t = threadIdx.x;
  const int i0 = blockIdx.x * 16;
  const int i_loc = t >> 4;        // 0..15 row for w-compute
  const int jsel  = t & 15;        // 16 threads/row, 4 j each
  const int cc    = t >> 2;        // 0..63 row for WhT staging
  const int joff  = (t & 3) * 16;  // j offset for WhT staging

  const float f1v = f1[i0 + i_loc];
  const int* adj_row = adj + (size_t)(i0 + i_loc) * N + jsel * 4;
  const float* f2p = f2 + jsel * 4;
  const uint16_t* vrow = whT + (size_t)cc * N + joff;

  // prefetch chunk 0
  int4   adjv = *(const int4*)(adj_row);
  float4 f2v  = *(const float4*)(f2p);
  int4   wa   = *(const int4*)(vrow);
  int4   wb   = *(const int4*)(vrow + 8);

  const int lane = t & 63;
  const int wv   = t >> 6;         // wave id 0..3
  const int arow = lane & 15;
  const int aq   = lane >> 4;
  const int c0   = wv * 16;        // this wave's FOUT slice

  f4v acc = {0.f, 0.f, 0.f, 0.f};
  float den_acc = 0.f;

  for (int jc = 0; jc < N / 64; ++jc) {
    // ---- compute 4 attention weights from current regs ----
    float e0 = f1v + f2v.x; e0 = fmaxf(e0, 0.2f * e0);
    float e1 = f1v + f2v.y; e1 = fmaxf(e1, 0.2f * e1);
    float e2 = f1v + f2v.z; e2 = fmaxf(e2, 0.2f * e2);
    float e3 = f1v + f2v.w; e3 = fmaxf(e3, 0.2f * e3);
    float w0 = (adjv.x > 0) ? __expf(e0) : 0.f;
    float w1 = (adjv.y > 0) ? __expf(e1) : 0.f;
    float w2 = (adjv.z > 0) ? __expf(e2) : 0.f;
    float w3 = (adjv.w > 0) ? __expf(e3) : 0.f;
    uint32_t u0 = f2bf(w0), u1 = f2bf(w1), u2 = f2bf(w2), u3 = f2bf(w3);
    // denominator from bf16-rounded weights (consistent with numerator)
    den_acc += __uint_as_float(u0 << 16) + __uint_as_float(u1 << 16)
             + __uint_as_float(u2 << 16) + __uint_as_float(u3 << 16);
    *(uint2*)&w_lds[i_loc][jsel * 4] = make_uint2(u0 | (u1 << 16), u2 | (u3 << 16));
    // stage WhT tile (64c x 64j bf16)
    *(int4*)&v_lds[cc][joff]     = wa;
    *(int4*)&v_lds[cc][joff + 8] = wb;
    // ---- prefetch next chunk ----
    if (jc + 1 < N / 64) {
      int jn = (jc + 1) * 64;
      adjv = *(const int4*)(adj_row + jn);
      f2v  = *(const float4*)(f2p + jn);
      wa   = *(const int4*)(vrow + jn);
      wb   = *(const int4*)(vrow + jn + 8);
    }
    __syncthreads();
    // ---- MFMA: A = w tile (16i x 64j), B = Wh tile (64j x 16c slice) ----
    s8v a0 = *(const s8v*)&w_lds[arow][aq * 8];
    s8v a1 = *(const s8v*)&w_lds[arow][32 + aq * 8];
    s8v b0 = *(const s8v*)&v_lds[c0 + arow][aq * 8];
    s8v b1 = *(const s8v*)&v_lds[c0 + arow][32 + aq * 8];
    acc = __builtin_amdgcn_mfma_f32_16x16x32_bf16(a0, b0, acc, 0, 0, 0);
    acc = __builtin_amdgcn_mfma_f32_16x16x32_bf16(a1, b1, acc, 0, 0, 0);
    __syncthreads();
  }

  // ---- denominator reduction ----
  den_lds[i_loc][jsel] = den_acc;
  __syncthreads();
  if (t < 16) {
    float s = 0.f;
    #pragma unroll
    for (int u = 0; u < 16; ++u) s += den_lds[t][u];
    den_fin[t] = s;
  }
  __syncthreads();

  // ---- epilogue: divide + elu, C/D layout col=lane&15, row=(lane>>4)*4+reg ----
  #pragma unroll
  for (int r = 0; r < 4; ++r) {
    int i_row = aq * 4 + r;
    float hp = acc[r] / den_fin[i_row];
    float o = (hp > 0.f) ? hp : (__expf(hp) - 1.f);
    out[(size_t)(i0 + i_row) * FOUT + c0 + arow] = o;
  }
}

extern "C" void kernel_launch(void* const* d_in, const int* in_sizes, int n_in,
                              void* d_out, int out_size, void* d_ws, size_t ws_size,
                              hipStream_t stream) {
  const float* h   = (const float*)d_in[0];
  const int*   adj = (const int*)d_in[1];
  const float* W   = (const float*)d_in[2];
  const float* a   = (const float*)d_in[3];
  float* out = (float*)d_out;

  float* f1 = (float*)d_ws;                 // 8192 f32
  float* f2 = f1 + N;                       // 8192 f32
  uint16_t* whT = (uint16_t*)(f2 + N);      // 64*8192 bf16 = 1 MB

  gat_prep<<<N / 8, 64, 0, stream>>>(h, W, a, f1, f2, whT);
  gat_main<<<N / 16, 256, 0, stream>>>(adj, f1, f2, whT, out);
}

// Round 2
// 436.910 us; speedup vs baseline: 1.0276x; 1.0276x over previous
//
#include <hip/hip_runtime.h>
#include <hip/hip_bf16.h>
#include <stdint.h>

#define N 8192
#define FIN 256
#define FOUT 64

typedef __attribute__((ext_vector_type(8))) short s8v;
typedef __attribute__((ext_vector_type(4))) float f4v;

// float -> bf16 bits, round-to-nearest-even
__device__ __forceinline__ uint32_t f2bf(float f) {
  uint32_t u = __float_as_uint(f);
  return (u + 0x7FFFu + ((u >> 16) & 1u)) >> 16;
}

// Kernel A: Wh = h@W (fp32 in regs), f1 = Wh@a1, f2 = Wh@a2, store WhT bf16 [64][8192]
__global__ __launch_bounds__(64) void gat_prep(
    const float* __restrict__ h, const float* __restrict__ W,
    const float* __restrict__ a,
    float* __restrict__ f1, float* __restrict__ f2,
    uint16_t* __restrict__ whT)
{
  const int c = threadIdx.x;        // 0..63 = output feature
  const int i0 = blockIdx.x * 8;    // 8 rows per block
  float acc[8] = {0.f, 0.f, 0.f, 0.f, 0.f, 0.f, 0.f, 0.f};
  #pragma unroll 4
  for (int k = 0; k < FIN; ++k) {
    float wv = W[k * FOUT + c];              // coalesced across lanes
    #pragma unroll
    for (int r = 0; r < 8; ++r)              // h index block-uniform -> s_load
      acc[r] += h[(size_t)(i0 + r) * FIN + k] * wv;
  }
  // lane c holds Wh[i0+r][c] == WhT[c][i0+r]: pack 8 bf16, one 16B store
  uint32_t b[8];
  #pragma unroll
  for (int r = 0; r < 8; ++r) b[r] = f2bf(acc[r]);
  int4 pk;
  pk.x = (int)(b[0] | (b[1] << 16));
  pk.y = (int)(b[2] | (b[3] << 16));
  pk.z = (int)(b[4] | (b[5] << 16));
  pk.w = (int)(b[6] | (b[7] << 16));
  *(int4*)(whT + (size_t)c * N + i0) = pk;

  const float a1 = a[c], a2 = a[FOUT + c];
  #pragma unroll
  for (int r = 0; r < 8; ++r) {
    float v1 = acc[r] * a1;
    float v2 = acc[r] * a2;
    #pragma unroll
    for (int m = 32; m > 0; m >>= 1) {
      v1 += __shfl_xor(v1, m, 64);
      v2 += __shfl_xor(v2, m, 64);
    }
    if (c == 0) { f1[i0 + r] = v1; f2[i0 + r] = v2; }
  }
}

// Build one MFMA A-fragment (8 bf16 attention weights) in registers.
// Lane covers row m, cols [j..j+7]. Accumulates bf16-rounded weights into den.
__device__ __forceinline__ s8v make_afrag(float f1v, const int* __restrict__ ap,
                                          const float* __restrict__ fp, float& den) {
  int4 c0 = *(const int4*)ap;
  int4 c1 = *(const int4*)(ap + 4);
  float4 g0 = *(const float4*)fp;
  float4 g1 = *(const float4*)(fp + 4);
  float e0 = f1v + g0.x; e0 = fmaxf(e0, 0.2f * e0); float w0 = (c0.x > 0) ? __expf(e0) : 0.f;
  float e1 = f1v + g0.y; e1 = fmaxf(e1, 0.2f * e1); float w1 = (c0.y > 0) ? __expf(e1) : 0.f;
  float e2 = f1v + g0.z; e2 = fmaxf(e2, 0.2f * e2); float w2 = (c0.z > 0) ? __expf(e2) : 0.f;
  float e3 = f1v + g0.w; e3 = fmaxf(e3, 0.2f * e3); float w3 = (c0.w > 0) ? __expf(e3) : 0.f;
  float e4 = f1v + g1.x; e4 = fmaxf(e4, 0.2f * e4); float w4 = (c1.x > 0) ? __expf(e4) : 0.f;
  float e5 = f1v + g1.y; e5 = fmaxf(e5, 0.2f * e5); float w5 = (c1.y > 0) ? __expf(e5) : 0.f;
  float e6 = f1v + g1.z; e6 = fmaxf(e6, 0.2f * e6); float w6 = (c1.z > 0) ? __expf(e6) : 0.f;
  float e7 = f1v + g1.w; e7 = fmaxf(e7, 0.2f * e7); float w7 = (c1.w > 0) ? __expf(e7) : 0.f;
  uint32_t b0 = f2bf(w0), b1 = f2bf(w1), b2 = f2bf(w2), b3 = f2bf(w3);
  uint32_t b4 = f2bf(w4), b5 = f2bf(w5), b6 = f2bf(w6), b7 = f2bf(w7);
  // denominator from the bf16-rounded weights (consistent with MFMA numerator)
  den += __uint_as_float(b0 << 16) + __uint_as_float(b1 << 16)
       + __uint_as_float(b2 << 16) + __uint_as_float(b3 << 16)
       + __uint_as_float(b4 << 16) + __uint_as_float(b5 << 16)
       + __uint_as_float(b6 << 16) + __uint_as_float(b7 << 16);
  union { s8v v; uint32_t u[4]; } r;
  r.u[0] = b0 | (b1 << 16);
  r.u[1] = b2 | (b3 << 16);
  r.u[2] = b4 | (b5 << 16);
  r.u[3] = b6 | (b7 << 16);
  return r.v;
}

// Kernel B: barrier-free flash GAT. One wave = 16 rows x (N/4) cols partial.
// A-fragments built in registers from adj/f1/f2; B-fragments loaded from
// global whT (1 MB, L1/L2-resident). No LDS, no __syncthreads.
__global__ __launch_bounds__(256) void gat_main2(
    const int* __restrict__ adj, const float* __restrict__ f1,
    const float* __restrict__ f2, const uint16_t* __restrict__ whT,
    float* __restrict__ pnum, float* __restrict__ pden)
{
  const int t = threadIdx.x;
  const int wave = t >> 6;
  const int lane = t & 63;
  const int task = blockIdx.x * 4 + wave;   // 0..2047
  const int group = task >> 2;              // 16-row group
  const int quarter = task & 3;             // j-quarter
  const int i0 = group * 16;
  const int jb = quarter * (N / 4);
  const int m  = lane & 15;                 // A row / B col
  const int kg = lane >> 4;                 // k-group (8 elems each)

  const float f1v = f1[i0 + m];
  const int*      ap  = adj + (size_t)(i0 + m) * N + jb + kg * 8;
  const float*    fp  = f2 + jb + kg * 8;
  const uint16_t* bp0 = whT + (size_t)m * N + jb + kg * 8;

  f4v acc0 = {0.f, 0.f, 0.f, 0.f};
  f4v acc1 = acc0, acc2 = acc0, acc3 = acc0;
  float den = 0.f;

  #pragma unroll 2
  for (int jc = 0; jc < (N / 4) / 64; ++jc) {
    const int j0 = jc * 64;
    s8v a0 = make_afrag(f1v, ap + j0,      fp + j0,      den);
    s8v a1 = make_afrag(f1v, ap + j0 + 32, fp + j0 + 32, den);
    const uint16_t* bp = bp0 + j0;
    s8v b00 = *(const s8v*)(bp);
    s8v b01 = *(const s8v*)(bp + 32);
    s8v b10 = *(const s8v*)(bp + 16 * N);
    s8v b11 = *(const s8v*)(bp + 16 * N + 32);
    s8v b20 = *(const s8v*)(bp + 32 * N);
    s8v b21 = *(const s8v*)(bp + 32 * N + 32);
    s8v b30 = *(const s8v*)(bp + 48 * N);
    s8v b31 = *(const s8v*)(bp + 48 * N + 32);
    acc0 = __builtin_amdgcn_mfma_f32_16x16x32_bf16(a0, b00, acc0, 0, 0, 0);
    acc0 = __builtin_amdgcn_mfma_f32_16x16x32_bf16(a1, b01, acc0, 0, 0, 0);
    acc1 = __builtin_amdgcn_mfma_f32_16x16x32_bf16(a0, b10, acc1, 0, 0, 0);
    acc1 = __builtin_amdgcn_mfma_f32_16x16x32_bf16(a1, b11, acc1, 0, 0, 0);
    acc2 = __builtin_amdgcn_mfma_f32_16x16x32_bf16(a0, b20, acc2, 0, 0, 0);
    acc2 = __builtin_amdgcn_mfma_f32_16x16x32_bf16(a1, b21, acc2, 0, 0, 0);
    acc3 = __builtin_amdgcn_mfma_f32_16x16x32_bf16(a0, b30, acc3, 0, 0, 0);
    acc3 = __builtin_amdgcn_mfma_f32_16x16x32_bf16(a1, b31, acc3, 0, 0, 0);
  }

  // den: sum across the 4 k-groups of this row (lanes m, m+16, m+32, m+48)
  den += __shfl_xor(den, 16, 64);
  den += __shfl_xor(den, 32, 64);

  // store fp32 partials; C/D layout: col = lane&15, row = (lane>>4)*4 + reg
  float* np = pnum + (size_t)task * (16 * 64);
  #pragma unroll
  for (int r = 0; r < 4; ++r) {
    int row = kg * 4 + r;
    np[row * 64 +      m] = acc0[r];
    np[row * 64 + 16 + m] = acc1[r];
    np[row * 64 + 32 + m] = acc2[r];
    np[row * 64 + 48 + m] = acc3[r];
  }
  if (lane < 16) pden[task * 16 + m] = den;
}

// Kernel C: combine 4 j-quarter partials, divide, ELU.
__global__ __launch_bounds__(256) void gat_combine(
    const float* __restrict__ pnum, const float* __restrict__ pden,
    float* __restrict__ out)
{
  const int idx = blockIdx.x * 256 + threadIdx.x;  // 0 .. 8192*64-1
  const int i = idx >> 6;
  const int c = idx & 63;
  const int g = i >> 4;
  const int r = i & 15;
  const size_t base = (size_t)g * 4 * 1024 + (size_t)r * 64 + c;
  float num = pnum[base] + pnum[base + 1024] + pnum[base + 2048] + pnum[base + 3072];
  const int db = g * 64 + r;
  float den = pden[db] + pden[db + 16] + pden[db + 32] + pden[db + 48];
  float hp = num / den;
  out[idx] = (hp > 0.f) ? hp : (__expf(hp) - 1.f);
}

extern "C" void kernel_launch(void* const* d_in, const int* in_sizes, int n_in,
                              void* d_out, int out_size, void* d_ws, size_t ws_size,
                              hipStream_t stream) {
  const float* h   = (const float*)d_in[0];
  const int*   adj = (const int*)d_in[1];
  const float* W   = (const float*)d_in[2];
  const float* a   = (const float*)d_in[3];
  float* out = (float*)d_out;

  float* f1 = (float*)d_ws;                     // 8192 f32
  float* f2 = f1 + N;                           // 8192 f32
  uint16_t* whT = (uint16_t*)(f2 + N);          // 64*8192 bf16 = 1 MB
  float* pnum = (float*)(whT + (size_t)FOUT * N);  // 2048*16*64 f32 = 8 MB
  float* pden = pnum + (size_t)2048 * 16 * 64;     // 2048*16 f32

  gat_prep<<<N / 8, 64, 0, stream>>>(h, W, a, f1, f2, whT);
  gat_main2<<<512, 256, 0, stream>>>(adj, f1, f2, whT, pnum, pden);
  gat_combine<<<(N * FOUT) / 256, 256, 0, stream>>>(pnum, pden, out);
}

// Round 3
// 421.865 us; speedup vs baseline: 1.0643x; 1.0357x over previous
//
#include <hip/hip_runtime.h>
#include <hip/hip_bf16.h>
#include <stdint.h>

#define N 8192
#define FIN 256
#define FOUT 64
#define QSPLIT 8                 // j-dimension split per 16-row group
#define NTASK (512 * QSPLIT)     // 4096 wave-tasks
#define JLEN (N / QSPLIT)        // 1024 columns per task
#define NITER (JLEN / 64)        // 16 chunks of 64 columns

typedef __attribute__((ext_vector_type(8))) short s8v;
typedef __attribute__((ext_vector_type(4))) float f4v;

// float -> bf16 bits, round-to-nearest-even
__device__ __forceinline__ uint32_t f2bf(float f) {
  uint32_t u = __float_as_uint(f);
  return (u + 0x7FFFu + ((u >> 16) & 1u)) >> 16;
}

// Kernel A: Wh = h@W (fp32 in regs), f1 = Wh@a1, f2 = Wh@a2, store WhT bf16 [64][8192]
// 4 rows per wave, 4 waves per block -> 512 blocks, 8 waves/CU (was 1 wave/SIMD).
__global__ __launch_bounds__(256) void gat_prep(
    const float* __restrict__ h, const float* __restrict__ W,
    const float* __restrict__ a,
    float* __restrict__ f1, float* __restrict__ f2,
    uint16_t* __restrict__ whT)
{
  const int c = threadIdx.x & 63;            // output feature
  const int wave = threadIdx.x >> 6;
  const int i0 = blockIdx.x * 16 + wave * 4; // 4 rows per wave
  float acc[4] = {0.f, 0.f, 0.f, 0.f};
  #pragma unroll 8
  for (int k = 0; k < FIN; ++k) {
    float wv = W[k * FOUT + c];              // coalesced across lanes
    #pragma unroll
    for (int r = 0; r < 4; ++r)              // h index wave-uniform -> s_load
      acc[r] += h[(size_t)(i0 + r) * FIN + k] * wv;
  }
  // lane c holds Wh[i0+r][c] == WhT[c][i0+r]: pack 4 bf16, one 8B store
  uint32_t b0 = f2bf(acc[0]), b1 = f2bf(acc[1]), b2 = f2bf(acc[2]), b3 = f2bf(acc[3]);
  int2 pk;
  pk.x = (int)(b0 | (b1 << 16));
  pk.y = (int)(b2 | (b3 << 16));
  *(int2*)(whT + (size_t)c * N + i0) = pk;

  const float a1 = a[c], a2 = a[FOUT + c];
  #pragma unroll
  for (int r = 0; r < 4; ++r) {
    float v1 = acc[r] * a1;
    float v2 = acc[r] * a2;
    #pragma unroll
    for (int m = 32; m > 0; m >>= 1) {
      v1 += __shfl_xor(v1, m, 64);
      v2 += __shfl_xor(v2, m, 64);
    }
    if (c == 0) { f1[i0 + r] = v1; f2[i0 + r] = v2; }
  }
}

// Build one MFMA A-fragment (8 bf16 attention weights) from pre-loaded regs.
__device__ __forceinline__ s8v make_afrag_r(float f1v, int4 c0, int4 c1,
                                            float4 g0, float4 g1, float& den) {
  float e0 = f1v + g0.x; e0 = fmaxf(e0, 0.2f * e0); float w0 = (c0.x > 0) ? __expf(e0) : 0.f;
  float e1 = f1v + g0.y; e1 = fmaxf(e1, 0.2f * e1); float w1 = (c0.y > 0) ? __expf(e1) : 0.f;
  float e2 = f1v + g0.z; e2 = fmaxf(e2, 0.2f * e2); float w2 = (c0.z > 0) ? __expf(e2) : 0.f;
  float e3 = f1v + g0.w; e3 = fmaxf(e3, 0.2f * e3); float w3 = (c0.w > 0) ? __expf(e3) : 0.f;
  float e4 = f1v + g1.x; e4 = fmaxf(e4, 0.2f * e4); float w4 = (c1.x > 0) ? __expf(e4) : 0.f;
  float e5 = f1v + g1.y; e5 = fmaxf(e5, 0.2f * e5); float w5 = (c1.y > 0) ? __expf(e5) : 0.f;
  float e6 = f1v + g1.z; e6 = fmaxf(e6, 0.2f * e6); float w6 = (c1.z > 0) ? __expf(e6) : 0.f;
  float e7 = f1v + g1.w; e7 = fmaxf(e7, 0.2f * e7); float w7 = (c1.w > 0) ? __expf(e7) : 0.f;
  uint32_t b0 = f2bf(w0), b1 = f2bf(w1), b2 = f2bf(w2), b3 = f2bf(w3);
  uint32_t b4 = f2bf(w4), b5 = f2bf(w5), b6 = f2bf(w6), b7 = f2bf(w7);
  // denominator from the bf16-rounded weights (consistent with MFMA numerator)
  den += __uint_as_float(b0 << 16) + __uint_as_float(b1 << 16)
       + __uint_as_float(b2 << 16) + __uint_as_float(b3 << 16)
       + __uint_as_float(b4 << 16) + __uint_as_float(b5 << 16)
       + __uint_as_float(b6 << 16) + __uint_as_float(b7 << 16);
  union { s8v v; uint32_t u[4]; } r;
  r.u[0] = b0 | (b1 << 16);
  r.u[1] = b2 | (b3 << 16);
  r.u[2] = b4 | (b5 << 16);
  r.u[3] = b6 | (b7 << 16);
  return r.v;
}

// Kernel B: barrier-free flash GAT. One wave = 16 rows x 1024 cols partial.
// Depth-1 register prefetch of adj/f2 (HBM-latency-critical); whT stays L1/L2-hot.
__global__ __launch_bounds__(256) void gat_main2(
    const int* __restrict__ adj, const float* __restrict__ f1,
    const float* __restrict__ f2, const uint16_t* __restrict__ whT,
    float* __restrict__ pnum, float* __restrict__ pden)
{
  const int t = threadIdx.x;
  const int wave = t >> 6;
  const int lane = t & 63;
  const int task = blockIdx.x * 4 + wave;   // 0..NTASK-1
  const int group = task / QSPLIT;          // 16-row group
  const int quarter = task % QSPLIT;        // j-slice
  const int i0 = group * 16;
  const int jb = quarter * JLEN;
  const int m  = lane & 15;                 // A row / B col
  const int kg = lane >> 4;                 // k-group (8 elems each)

  const float f1v = f1[i0 + m];
  const int*      ap  = adj + (size_t)(i0 + m) * N + jb + kg * 8;
  const float*    fp  = f2 + jb + kg * 8;
  const uint16_t* bp0 = whT + (size_t)m * N + jb + kg * 8;

  f4v acc0 = {0.f, 0.f, 0.f, 0.f};
  f4v acc1 = acc0, acc2 = acc0, acc3 = acc0;
  float den = 0.f;

  // prefetch chunk 0: adj + f2 for both afrags
  int4   pc0 = *(const int4*)(ap);
  int4   pc1 = *(const int4*)(ap + 4);
  int4   pc2 = *(const int4*)(ap + 32);
  int4   pc3 = *(const int4*)(ap + 36);
  float4 pg0 = *(const float4*)(fp);
  float4 pg1 = *(const float4*)(fp + 4);
  float4 pg2 = *(const float4*)(fp + 32);
  float4 pg3 = *(const float4*)(fp + 36);

  #pragma unroll 1
  for (int jc = 0; jc < NITER; ++jc) {
    const int j0 = jc * 64;
    int4 c0 = pc0, c1 = pc1, c2 = pc2, c3 = pc3;
    float4 g0 = pg0, g1 = pg1, g2 = pg2, g3 = pg3;
    // issue next chunk's HBM loads before consuming current
    if (jc + 1 < NITER) {
      const int jn = j0 + 64;
      pc0 = *(const int4*)(ap + jn);
      pc1 = *(const int4*)(ap + jn + 4);
      pc2 = *(const int4*)(ap + jn + 32);
      pc3 = *(const int4*)(ap + jn + 36);
      pg0 = *(const float4*)(fp + jn);
      pg1 = *(const float4*)(fp + jn + 4);
      pg2 = *(const float4*)(fp + jn + 32);
      pg3 = *(const float4*)(fp + jn + 36);
    }
    s8v a0 = make_afrag_r(f1v, c0, c1, g0, g1, den);
    s8v a1 = make_afrag_r(f1v, c2, c3, g2, g3, den);
    const uint16_t* bp = bp0 + j0;
    s8v b00 = *(const s8v*)(bp);
    s8v b01 = *(const s8v*)(bp + 32);
    s8v b10 = *(const s8v*)(bp + 16 * N);
    s8v b11 = *(const s8v*)(bp + 16 * N + 32);
    s8v b20 = *(const s8v*)(bp + 32 * N);
    s8v b21 = *(const s8v*)(bp + 32 * N + 32);
    s8v b30 = *(const s8v*)(bp + 48 * N);
    s8v b31 = *(const s8v*)(bp + 48 * N + 32);
    acc0 = __builtin_amdgcn_mfma_f32_16x16x32_bf16(a0, b00, acc0, 0, 0, 0);
    acc0 = __builtin_amdgcn_mfma_f32_16x16x32_bf16(a1, b01, acc0, 0, 0, 0);
    acc1 = __builtin_amdgcn_mfma_f32_16x16x32_bf16(a0, b10, acc1, 0, 0, 0);
    acc1 = __builtin_amdgcn_mfma_f32_16x16x32_bf16(a1, b11, acc1, 0, 0, 0);
    acc2 = __builtin_amdgcn_mfma_f32_16x16x32_bf16(a0, b20, acc2, 0, 0, 0);
    acc2 = __builtin_amdgcn_mfma_f32_16x16x32_bf16(a1, b21, acc2, 0, 0, 0);
    acc3 = __builtin_amdgcn_mfma_f32_16x16x32_bf16(a0, b30, acc3, 0, 0, 0);
    acc3 = __builtin_amdgcn_mfma_f32_16x16x32_bf16(a1, b31, acc3, 0, 0, 0);
  }

  // den: sum across the 4 k-groups of this row (lanes m, m+16, m+32, m+48)
  den += __shfl_xor(den, 16, 64);
  den += __shfl_xor(den, 32, 64);

  // store fp32 partials; C/D layout: col = lane&15, row = (lane>>4)*4 + reg
  float* np = pnum + (size_t)task * (16 * 64);
  #pragma unroll
  for (int r = 0; r < 4; ++r) {
    int row = kg * 4 + r;
    np[row * 64 +      m] = acc0[r];
    np[row * 64 + 16 + m] = acc1[r];
    np[row * 64 + 32 + m] = acc2[r];
    np[row * 64 + 48 + m] = acc3[r];
  }
  if (lane < 16) pden[task * 16 + m] = den;
}

// Kernel C: combine QSPLIT j-slice partials, divide, ELU.
__global__ __launch_bounds__(256) void gat_combine(
    const float* __restrict__ pnum, const float* __restrict__ pden,
    float* __restrict__ out)
{
  const int idx = blockIdx.x * 256 + threadIdx.x;  // 0 .. 8192*64-1
  const int i = idx >> 6;
  const int c = idx & 63;
  const int g = i >> 4;
  const int r = i & 15;
  const size_t base = (size_t)g * QSPLIT * 1024 + (size_t)r * 64 + c;
  float num = 0.f;
  #pragma unroll
  for (int q = 0; q < QSPLIT; ++q) num += pnum[base + (size_t)q * 1024];
  const int db = g * (QSPLIT * 16) + r;
  float den = 0.f;
  #pragma unroll
  for (int q = 0; q < QSPLIT; ++q) den += pden[db + q * 16];
  float hp = num / den;
  out[idx] = (hp > 0.f) ? hp : (__expf(hp) - 1.f);
}

extern "C" void kernel_launch(void* const* d_in, const int* in_sizes, int n_in,
                              void* d_out, int out_size, void* d_ws, size_t ws_size,
                              hipStream_t stream) {
  const float* h   = (const float*)d_in[0];
  const int*   adj = (const int*)d_in[1];
  const float* W   = (const float*)d_in[2];
  const float* a   = (const float*)d_in[3];
  float* out = (float*)d_out;

  float* f1 = (float*)d_ws;                     // 8192 f32
  float* f2 = f1 + N;                           // 8192 f32
  uint16_t* whT = (uint16_t*)(f2 + N);          // 64*8192 bf16 = 1 MB
  float* pnum = (float*)(whT + (size_t)FOUT * N);   // NTASK*16*64 f32 = 16 MB
  float* pden = pnum + (size_t)NTASK * 16 * 64;     // NTASK*16 f32

  gat_prep<<<N / 16, 256, 0, stream>>>(h, W, a, f1, f2, whT);
  gat_main2<<<NTASK / 4, 256, 0, stream>>>(adj, f1, f2, whT, pnum, pden);
  gat_combine<<<(N * FOUT) / 256, 256, 0, stream>>>(pnum, pden, out);
}